// Round 6
// baseline (162.812 us; speedup 1.0000x reference)
//
#include <hip/hip_runtime.h>

// Adaptive downsampler: B=8, C=3, 1024x1024 -> 512x512, K2=9 taps,
// bilinear gather from reflect-padded (pad=1) image, weighted by kernels.
// R5: XCD swizzle + nt stream loads (both proven) with the low-VGPR rolled
//     ky loop from R2 (9 stream loads/iter, VGPR ~40-48 -> 8 waves/SIMD TLP)
//     instead of the 27-wide preload (VGPR 88, occupancy 18%).
constexpr int B_  = 8;
constexpr int C_  = 3;
constexpr int H_  = 1024;
constexpr int W_  = 1024;
constexpr int HO_ = 512;
constexpr int WO_ = 512;
constexpr int K2_ = 9;
constexpr int KS_ = 3;
constexpr int HP_ = H_ + 2;   // padded height (pad=1)
constexpr int WP_ = W_ + 2;   // padded width
constexpr int NBLK_ = (B_ * HO_ * WO_) / 256;   // 8192 blocks
constexpr int NXCD_ = 8;

__device__ __forceinline__ float2 ld2(const float* p) {
    float2 r;
    __builtin_memcpy(&r, p, sizeof(float2));   // global_load_dwordx2
    return r;
}

__global__ __launch_bounds__(256) void ds_kernel(
    const float* __restrict__ img,
    const float* __restrict__ kern,
    const float* __restrict__ offh,
    const float* __restrict__ offv,
    const float* __restrict__ unit_p,
    float* __restrict__ out)
{
    const int HWo = HO_ * WO_;                       // 262144

    // XCD swizzle: block i runs on XCD i%8 (round-robin dispatch).
    // Each XCD gets a contiguous slab of 1024 blocks = one full batch,
    // oy-ordered, so the image y-window stays in that XCD's L2.
    const int wg  = blockIdx.x;
    const int nid = (wg & (NXCD_ - 1)) * (NBLK_ / NXCD_) + (wg >> 3);
    const int idx = nid * 256 + threadIdx.x;

    const int ox = idx & (WO_ - 1);
    const int oy = (idx >> 9) & (HO_ - 1);
    const int b  = idx >> 18;

    const float unit = unit_p[0];
    const float* imgb = img + (size_t)b * (C_ * H_ * W_);
    const int kbase = b * (K2_ * HWo) + oy * WO_ + ox;   // < 2^25

    // (ox+0.5)/WO*W - 0.5 == 2*ox + 0.5  (exact in fp32; W/WO = 2)
    const float cx = 2.0f * (float)ox + 0.5f;
    const float cy = 2.0f * (float)oy + 0.5f;

    float acc0 = 0.0f, acc1 = 0.0f, acc2 = 0.0f;

#pragma unroll 1
    for (int ky = 0; ky < KS_; ++ky) {
        const float fky = (float)ky;

        // 9 stream loads for this ky row, all in flight (read-once -> nt).
        float wk[KS_], oh[KS_], ov[KS_];
#pragma unroll
        for (int kx = 0; kx < KS_; ++kx) {
            const int k = ky * KS_ + kx;
            wk[kx] = __builtin_nontemporal_load(kern + kbase + k * HWo);
            oh[kx] = __builtin_nontemporal_load(offh + kbase + k * HWo);
            ov[kx] = __builtin_nontemporal_load(offv + kbase + k * HWo);
        }

#pragma unroll
        for (int kx = 0; kx < KS_; ++kx) {
            const float px = cx + (float)kx + oh[kx] * unit;
            const float py = cy + fky       + ov[kx] * unit;

            const float fx = floorf(px);
            const float fy = floorf(py);
            const float a  = px - fx;   // alpha
            const float bt = py - fy;   // beta

            // clip in PADDED coordinates [0, WP-1] / [0, HP-1]
            int xL = (int)fx; xL = xL < 0 ? 0 : (xL > WP_ - 1 ? WP_ - 1 : xL);
            int xR = xL + 1;  xR = xR > WP_ - 1 ? WP_ - 1 : xR;
            int yT = (int)fy; yT = yT < 0 ? 0 : (yT > HP_ - 1 ? HP_ - 1 : yT);
            int yB = yT + 1;  yB = yB > HP_ - 1 ? HP_ - 1 : yB;

            // padded -> original with reflect (pad=1): j=i-1; -1->1; H->H-2
            int xl = xL - 1; xl = (xl < 0) ? -xl : (xl >= W_ ? 2 * W_ - 2 - xl : xl);
            int xr = xR - 1; xr = (xr < 0) ? -xr : (xr >= W_ ? 2 * W_ - 2 - xr : xr);
            int yt = yT - 1; yt = (yt < 0) ? -yt : (yt >= H_ ? 2 * H_ - 2 - yt : yt);
            int yb = yB - 1; yb = (yb < 0) ? -yb : (yb >= H_ ? 2 * H_ - 2 - yb : yb);

            // |xl - xr| <= 1 always; base = min <= W-2, so [base,base+1] in-bounds.
            const int base = xl < xr ? xl : xr;
            const float ax0 = ((xl == base) ? (1.0f - a) : 0.0f)
                            + ((xr == base) ? a : 0.0f);
            const float ax1 = 1.0f - ax0;

            const float wt = wk[kx] * (1.0f - bt);
            const float wb = wk[kx] * bt;

            const int r0 = yt * W_ + base;
            const int r1 = yb * W_ + base;

            {
                const float2 v = ld2(imgb + r0);
                const float2 u = ld2(imgb + r1);
                acc0 = fmaf(wt, fmaf(ax0, v.x, ax1 * v.y),
                       fmaf(wb, fmaf(ax0, u.x, ax1 * u.y), acc0));
            }
            {
                const float2 v = ld2(imgb + H_ * W_ + r0);
                const float2 u = ld2(imgb + H_ * W_ + r1);
                acc1 = fmaf(wt, fmaf(ax0, v.x, ax1 * v.y),
                       fmaf(wb, fmaf(ax0, u.x, ax1 * u.y), acc1));
            }
            {
                const float2 v = ld2(imgb + 2 * H_ * W_ + r0);
                const float2 u = ld2(imgb + 2 * H_ * W_ + r1);
                acc2 = fmaf(wt, fmaf(ax0, v.x, ax1 * v.y),
                       fmaf(wb, fmaf(ax0, u.x, ax1 * u.y), acc2));
            }
        }
    }

    const int obase = b * (C_ * HWo) + oy * WO_ + ox;
    out[obase]           = acc0;
    out[obase + HWo]     = acc1;
    out[obase + 2 * HWo] = acc2;
}

extern "C" void kernel_launch(void* const* d_in, const int* in_sizes, int n_in,
                              void* d_out, int out_size, void* d_ws, size_t ws_size,
                              hipStream_t stream) {
    const float* img  = (const float*)d_in[0];
    const float* kern = (const float*)d_in[1];
    const float* offh = (const float*)d_in[2];
    const float* offv = (const float*)d_in[3];
    const float* unit = (const float*)d_in[4];
    float* out = (float*)d_out;

    ds_kernel<<<NBLK_, 256, 0, stream>>>(img, kern, offh, offv, unit, out);
}

// Round 7
// 126.328 us; speedup vs baseline: 1.2888x; 1.2888x over previous
//
#include <hip/hip_runtime.h>

// Adaptive downsampler: B=8, C=3, 1024x1024 -> 512x512, K2=9 taps,
// bilinear gather from reflect-padded (pad=1) image, weighted by kernels.
// R6 = R4 (best, 143.8us: 27-wide nt preload, full unroll, ld2 gathers,
//      XCD slab swizzle, plain stores) + 2D block remap: each block is a
//      64x4 output patch (wave w -> oy quad row w, lanes -> 64 ox), so the
//      4 waves of a CU share the image y-window in L1 (~75% row overlap)
//      instead of pulling it from L2 per-row.
constexpr int B_  = 8;
constexpr int C_  = 3;
constexpr int H_  = 1024;
constexpr int W_  = 1024;
constexpr int HO_ = 512;
constexpr int WO_ = 512;
constexpr int K2_ = 9;
constexpr int KS_ = 3;
constexpr int HP_ = H_ + 2;   // padded height (pad=1)
constexpr int WP_ = W_ + 2;   // padded width
constexpr int NBLK_ = (B_ * HO_ * WO_) / 256;   // 8192 blocks
constexpr int NXCD_ = 8;

__device__ __forceinline__ float2 ld2(const float* p) {
    float2 r;
    __builtin_memcpy(&r, p, sizeof(float2));   // global_load_dwordx2
    return r;
}

__global__ __launch_bounds__(256) void ds_kernel(
    const float* __restrict__ img,
    const float* __restrict__ kern,
    const float* __restrict__ offh,
    const float* __restrict__ offv,
    const float* __restrict__ unit_p,
    float* __restrict__ out)
{
    const int HWo = HO_ * WO_;                       // 262144

    // XCD swizzle: block i runs on XCD i%8 (round-robin dispatch).
    // nid in [b*1024, b*1024+1023] = batch b -> XCD b owns one batch.
    const int wg  = blockIdx.x;
    const int nid = (wg & (NXCD_ - 1)) * (NBLK_ / NXCD_) + (wg >> 3);

    // 2D patch decode: nid = b*1024 + oyt*8 + oxt
    //   oyt 0..127 (quad of oy rows), oxt 0..7 (64-px ox chunk)
    // wave w of the block -> oy = oyt*4 + w; lanes -> ox = oxt*64 + lane.
    const int b   = nid >> 10;
    const int q   = nid & 1023;
    const int oyt = q >> 3;
    const int oxt = q & 7;
    const int wv  = threadIdx.x >> 6;
    const int ln  = threadIdx.x & 63;
    const int oy  = oyt * 4 + wv;
    const int ox  = oxt * 64 + ln;

    const float unit = unit_p[0];
    const float* imgb = img + (size_t)b * (C_ * H_ * W_);
    const int kbase = b * (K2_ * HWo) + oy * WO_ + ox;   // < 2^25

    // (ox+0.5)/WO*W - 0.5 == 2*ox + 0.5  (exact in fp32; W/WO = 2)
    const float cx = 2.0f * (float)ox + 0.5f;
    const float cy = 2.0f * (float)oy + 0.5f;

    // Phase 1: all 27 stream loads in flight (read-once -> nontemporal).
    float wk[K2_], oh[K2_], ov[K2_];
#pragma unroll
    for (int k = 0; k < K2_; ++k) {
        wk[k] = __builtin_nontemporal_load(kern + kbase + k * HWo);
        oh[k] = __builtin_nontemporal_load(offh + kbase + k * HWo);
        ov[k] = __builtin_nontemporal_load(offv + kbase + k * HWo);
    }

    float acc0 = 0.0f, acc1 = 0.0f, acc2 = 0.0f;

    // Phase 2: taps, fully unrolled (compile-time k -> regs, not scratch).
#pragma unroll
    for (int k = 0; k < K2_; ++k) {
        const float px = cx + (float)(k % KS_) + oh[k] * unit;
        const float py = cy + (float)(k / KS_) + ov[k] * unit;

        const float fx = floorf(px);
        const float fy = floorf(py);
        const float a  = px - fx;   // alpha
        const float bt = py - fy;   // beta

        // clip in PADDED coordinates [0, WP-1] / [0, HP-1]
        int xL = (int)fx; xL = xL < 0 ? 0 : (xL > WP_ - 1 ? WP_ - 1 : xL);
        int xR = xL + 1;  xR = xR > WP_ - 1 ? WP_ - 1 : xR;
        int yT = (int)fy; yT = yT < 0 ? 0 : (yT > HP_ - 1 ? HP_ - 1 : yT);
        int yB = yT + 1;  yB = yB > HP_ - 1 ? HP_ - 1 : yB;

        // padded -> original with reflect (pad=1): j=i-1; -1->1; H->H-2
        int xl = xL - 1; xl = (xl < 0) ? -xl : (xl >= W_ ? 2 * W_ - 2 - xl : xl);
        int xr = xR - 1; xr = (xr < 0) ? -xr : (xr >= W_ ? 2 * W_ - 2 - xr : xr);
        int yt = yT - 1; yt = (yt < 0) ? -yt : (yt >= H_ ? 2 * H_ - 2 - yt : yt);
        int yb = yB - 1; yb = (yb < 0) ? -yb : (yb >= H_ ? 2 * H_ - 2 - yb : yb);

        // |xl - xr| <= 1 always; base = min <= W-2, so [base,base+1] in-bounds.
        const int base = xl < xr ? xl : xr;
        const float ax0 = ((xl == base) ? (1.0f - a) : 0.0f)
                        + ((xr == base) ? a : 0.0f);
        const float ax1 = 1.0f - ax0;

        const float wt = wk[k] * (1.0f - bt);
        const float wb = wk[k] * bt;

        const int r0 = yt * W_ + base;
        const int r1 = yb * W_ + base;

        {
            const float2 v = ld2(imgb + r0);
            const float2 u = ld2(imgb + r1);
            acc0 = fmaf(wt, fmaf(ax0, v.x, ax1 * v.y),
                   fmaf(wb, fmaf(ax0, u.x, ax1 * u.y), acc0));
        }
        {
            const float2 v = ld2(imgb + H_ * W_ + r0);
            const float2 u = ld2(imgb + H_ * W_ + r1);
            acc1 = fmaf(wt, fmaf(ax0, v.x, ax1 * v.y),
                   fmaf(wb, fmaf(ax0, u.x, ax1 * u.y), acc1));
        }
        {
            const float2 v = ld2(imgb + 2 * H_ * W_ + r0);
            const float2 u = ld2(imgb + 2 * H_ * W_ + r1);
            acc2 = fmaf(wt, fmaf(ax0, v.x, ax1 * v.y),
                   fmaf(wb, fmaf(ax0, u.x, ax1 * u.y), acc2));
        }
    }

    const int obase = b * (C_ * HWo) + oy * WO_ + ox;
    out[obase]           = acc0;
    out[obase + HWo]     = acc1;
    out[obase + 2 * HWo] = acc2;
}

extern "C" void kernel_launch(void* const* d_in, const int* in_sizes, int n_in,
                              void* d_out, int out_size, void* d_ws, size_t ws_size,
                              hipStream_t stream) {
    const float* img  = (const float*)d_in[0];
    const float* kern = (const float*)d_in[1];
    const float* offh = (const float*)d_in[2];
    const float* offv = (const float*)d_in[3];
    const float* unit = (const float*)d_in[4];
    float* out = (float*)d_out;

    ds_kernel<<<NBLK_, 256, 0, stream>>>(img, kern, offh, offv, unit, out);
}